// Round 1
// 1034.610 us; speedup vs baseline: 1.0501x; 1.0501x over previous
//
#include <hip/hip_runtime.h>
#include <cstdint>

#define B_ 4
#define T_ 2048
#define D_ 1024
#define E_ 8
#define F_ 4096
#define K_ 2
#define N_ (B_*T_)      // 8192 tokens
#define NR_ (N_*K_)     // 16384 routed slots

#define TM 128
#define BK 64
#define MAXP (NR_ + E_*TM)       // padded slot capacity (17408)
#define MAXMB (NR_/TM + E_)      // max M-blocks (136)

typedef __attribute__((ext_vector_type(8))) short short8;
typedef __attribute__((ext_vector_type(4))) float f32x4;

typedef const __attribute__((address_space(1))) unsigned int* gp1_t;
typedef __attribute__((address_space(3))) unsigned int* lp3_t;

__device__ __forceinline__ void gl_lds16(const void* g, void* l) {
    __builtin_amdgcn_global_load_lds((gp1_t)g, (lp3_t)l, 16, 0, 0);
}

__device__ __forceinline__ unsigned short f2b(float f) {
    union { float f; unsigned int u; } v; v.f = f;
    unsigned int u = v.u;
    return (unsigned short)((u + 0x7FFFu + ((u >> 16) & 1u)) >> 16);
}

__device__ __forceinline__ float b2f(unsigned short u) {
    union { unsigned int i; float f; } v; v.i = ((unsigned int)u) << 16;
    return v.f;
}

__device__ __forceinline__ float gelu_exact(float x) {
    return 0.5f * x * (1.0f + erff(x * 0.70710678118654752440f));
}

// ---------------- gate: fp32 logits, top-2, softmax ----------------
__global__ __launch_bounds__(256) void gate_kernel(
    const float* __restrict__ x, const float* __restrict__ Wg,
    const float* __restrict__ bg, int* __restrict__ topi,
    float* __restrict__ topw, int* __restrict__ counts) {
    int tid  = threadIdx.x;
    int lane = tid & 63;
    int tok  = blockIdx.x * 4 + (tid >> 6);
    int e = lane & 7;
    int c = lane >> 3;
    const float4* xp = (const float4*)(x + (size_t)tok * D_ + c * 128);
    const float*  wp = Wg + (size_t)(c * 128) * E_ + e;
    float acc = 0.f;
    #pragma unroll 8
    for (int i = 0; i < 32; ++i) {
        float4 xv = xp[i];
        acc += xv.x * wp[(i*4+0)*E_];
        acc += xv.y * wp[(i*4+1)*E_];
        acc += xv.z * wp[(i*4+2)*E_];
        acc += xv.w * wp[(i*4+3)*E_];
    }
    acc += __shfl_xor(acc, 8, 64);
    acc += __shfl_xor(acc, 16, 64);
    acc += __shfl_xor(acc, 32, 64);
    float logit = acc + bg[e];
    float v1 = -3.4e38f, v2 = -3.4e38f; int i1 = -1, i2 = -1;
    for (int ee = 0; ee < 8; ++ee) {
        float le = __shfl(logit, ee, 64);
        if (le > v1) { v2 = v1; i2 = i1; v1 = le; i1 = ee; }
        else if (le > v2) { v2 = le; i2 = ee; }
    }
    if (lane == 0) {
        float p2 = expf(v2 - v1);
        float s  = 1.0f + p2;
        topi[tok*2]   = i1; topw[tok*2]   = 1.0f / s;
        topi[tok*2+1] = i2; topw[tok*2+1] = p2 / s;
        atomicAdd(&counts[i1], 1);
        atomicAdd(&counts[i2], 1);
    }
}

// scan: padded offsets + flat M-block tables
__global__ void scan_kernel(const int* __restrict__ counts,
                            int* __restrict__ offs, int* __restrict__ cursors,
                            int* __restrict__ mb_e, int* __restrict__ mb_m0) {
    if (threadIdx.x == 0) {
        int s = 0, mb = 0;
        for (int e = 0; e < E_; ++e) {
            offs[e] = s; cursors[e] = s;
            int nb = (counts[e] + TM - 1) / TM;
            for (int i = 0; i < nb; ++i) { mb_e[mb] = e; mb_m0[mb] = s + i*TM; ++mb; }
            s += nb * TM;
        }
        offs[E_] = s;
        for (int b = mb; b < MAXMB; ++b) mb_e[b] = -1;
    }
}

__global__ __launch_bounds__(256) void scatter_kernel(
    const int* __restrict__ topi, int* __restrict__ cursors,
    int* __restrict__ perm, int* __restrict__ slots) {
    int t = blockIdx.x * blockDim.x + threadIdx.x;
    if (t >= N_) return;
    #pragma unroll
    for (int k = 0; k < K_; ++k) {
        int e = topi[t*2 + k];
        int pos = atomicAdd(&cursors[e], 1);
        perm[pos] = t;
        slots[t*2 + k] = pos;
    }
}

// ---------------- casts ----------------
__global__ __launch_bounds__(256) void castx_kernel(
    const float* __restrict__ x, unsigned short* __restrict__ xb) {
    int i = blockIdx.x * blockDim.x + threadIdx.x;   // over N*D/4
    float4 v = ((const float4*)x)[i];
    ushort4 o; o.x = f2b(v.x); o.y = f2b(v.y); o.z = f2b(v.z); o.w = f2b(v.w);
    ((ushort4*)xb)[i] = o;
}

// batched fp32 [R,C] -> bf16 [C,R]; 64x64 tile, vectorized
__global__ __launch_bounds__(256) void tcast_kernel(
    const float* __restrict__ src, unsigned short* __restrict__ dst, int R, int C) {
    __shared__ float tile[64][65];
    int rb = blockIdx.x * 64, cb = blockIdx.y * 64;
    const float* s = src + (size_t)blockIdx.z * R * C;
    unsigned short* d = dst + (size_t)blockIdx.z * R * C;
    int tx = threadIdx.x & 15, ty = threadIdx.x >> 4;   // 16 x 16
    #pragma unroll
    for (int i = 0; i < 4; ++i) {
        int r = ty + i*16;
        float4 v = *(const float4*)&s[(size_t)(rb + r) * C + cb + tx*4];
        tile[r][tx*4+0] = v.x; tile[r][tx*4+1] = v.y;
        tile[r][tx*4+2] = v.z; tile[r][tx*4+3] = v.w;
    }
    __syncthreads();
    #pragma unroll
    for (int i = 0; i < 4; ++i) {
        int c = ty + i*16;                               // dst row
        ushort4 o;
        o.x = f2b(tile[tx*4+0][c]);
        o.y = f2b(tile[tx*4+1][c]);
        o.z = f2b(tile[tx*4+2][c]);
        o.w = f2b(tile[tx*4+3][c]);
        *(ushort4*)&d[(size_t)(cb + c) * R + rb + tx*4] = o;
    }
}

// ---------------- GEMM1: H = gelu(Xb[perm] @ W1[e] + b1[e]) ----------------
// 128x128 tile, BK=64; grid (MAXMB, F/128); acc 4x4, 4 waves/SIMD
// T2 both-sides swizzle: LDS dest stays linear (global_load_lds), SOURCE chunk
// is pre-XOR'd by (row&7), READ chunk XOR'd the same way (rule 21).
__global__ __launch_bounds__(256, 4) void ffn1_kernel(
    const unsigned short* __restrict__ Xb, const unsigned short* __restrict__ W1t,
    const float* __restrict__ b1, const int* __restrict__ perm,
    const int* __restrict__ mb_e, const int* __restrict__ mb_m0,
    unsigned short* __restrict__ H) {
    int e = mb_e[blockIdx.x];
    if (e < 0) return;
    int m0 = mb_m0[blockIdx.x];
    int n0 = blockIdx.y * 128;
    const unsigned short* Bw = W1t + (size_t)e * F_ * D_;

    __shared__ __align__(16) unsigned short lA[128*BK];   // 16 KB
    __shared__ __align__(16) unsigned short lB[128*BK];   // 16 KB

    int t = threadIdx.x;
    int lane = t & 63;
    int wv = t >> 6;
    int wrow = (wv >> 1) * 64, wcol = (wv & 1) * 64;
    int lr = lane & 15, q = lane >> 4;
    int xork = lr & 7;        // read-side swizzle key (row&7 == lr&7)

    int sr = t >> 3;          // staging row 0..31 per pass
    int sc = ((t & 7) ^ (sr & 7)) * 8;   // pre-swizzled source chunk (ushorts)
    const unsigned short* pa[4];
    const unsigned short* pb[4];
    #pragma unroll
    for (int i = 0; i < 4; ++i) {
        int tok = perm[m0 + sr + 32*i];
        pa[i] = Xb + (size_t)tok * D_ + sc;
        pb[i] = Bw + (size_t)(n0 + sr + 32*i) * D_ + sc;
    }

    f32x4 acc[4][4];
    #pragma unroll
    for (int mi = 0; mi < 4; ++mi)
        #pragma unroll
        for (int ni = 0; ni < 4; ++ni)
            acc[mi][ni] = (f32x4){0.f, 0.f, 0.f, 0.f};

    for (int kk = 0; kk < D_/BK; ++kk) {
        int k0 = kk * BK;
        #pragma unroll
        for (int i = 0; i < 4; ++i) {
            gl_lds16(pa[i] + k0, &lA[i*2048 + t*8]);
            gl_lds16(pb[i] + k0, &lB[i*2048 + t*8]);
        }
        asm volatile("s_waitcnt vmcnt(0)" ::: "memory");
        __syncthreads();
        #pragma unroll
        for (int s = 0; s < 2; ++s) {
            short8 af[4], bf[4];
            #pragma unroll
            for (int mi = 0; mi < 4; ++mi)
                af[mi] = *(const short8*)&lA[(wrow + mi*16 + lr)*BK + (((s*4+q) ^ xork) * 8)];
            #pragma unroll
            for (int ni = 0; ni < 4; ++ni)
                bf[ni] = *(const short8*)&lB[(wcol + ni*16 + lr)*BK + (((s*4+q) ^ xork) * 8)];
            #pragma unroll
            for (int mi = 0; mi < 4; ++mi)
                #pragma unroll
                for (int ni = 0; ni < 4; ++ni)
                    acc[mi][ni] = __builtin_amdgcn_mfma_f32_16x16x32_bf16(
                        af[mi], bf[ni], acc[mi][ni], 0, 0, 0);
        }
        __syncthreads();
    }

    const float* b1e = b1 + (size_t)e * F_;
    #pragma unroll
    for (int mi = 0; mi < 4; ++mi) {
        int gr = m0 + wrow + mi*16 + q*4;
        #pragma unroll
        for (int ni = 0; ni < 4; ++ni) {
            int f = n0 + wcol + ni*16 + lr;
            float bb = b1e[f];
            #pragma unroll
            for (int r = 0; r < 4; ++r) {
                float h = gelu_exact(acc[mi][ni][r] + bb);
                H[(size_t)(gr + r) * F_ + f] = f2b(h);
            }
        }
    }
}

// ---------------- GEMM2: Y[p] = H[p] @ W2[e] + b2[e] (bf16 stores) ---------
// 128x128 tile, BK=64; grid (MAXMB, D/128)=1088 wg; acc 4x4, 4 waves/SIMD.
// Was 128x256 / 544 wg / 2 blk/CU: grid-starved + 3.9e7 bank-conflict cycles.
__global__ __launch_bounds__(256, 4) void ffn2_kernel(
    const unsigned short* __restrict__ H, const unsigned short* __restrict__ W2t,
    const float* __restrict__ b2,
    const int* __restrict__ mb_e, const int* __restrict__ mb_m0,
    unsigned short* __restrict__ Y) {
    int e = mb_e[blockIdx.x];
    if (e < 0) return;
    int m0 = mb_m0[blockIdx.x];
    int n0 = blockIdx.y * 128;
    const unsigned short* Bw = W2t + (size_t)e * D_ * F_;

    __shared__ __align__(16) unsigned short lA[128*BK];   // 16 KB
    __shared__ __align__(16) unsigned short lB[128*BK];   // 16 KB

    int t = threadIdx.x;
    int lane = t & 63;
    int wv = t >> 6;
    int wrow = (wv >> 1) * 64, wcol = (wv & 1) * 64;
    int lr = lane & 15, q = lane >> 4;
    int xork = lr & 7;

    int sr = t >> 3;
    int sc = ((t & 7) ^ (sr & 7)) * 8;   // pre-swizzled source chunk
    const unsigned short* pa[4];
    const unsigned short* pb[4];
    #pragma unroll
    for (int i = 0; i < 4; ++i) {
        pa[i] = H  + (size_t)(m0 + sr + 32*i) * F_ + sc;
        pb[i] = Bw + (size_t)(n0 + sr + 32*i) * F_ + sc;
    }

    f32x4 acc[4][4];
    #pragma unroll
    for (int mi = 0; mi < 4; ++mi)
        #pragma unroll
        for (int ni = 0; ni < 4; ++ni)
            acc[mi][ni] = (f32x4){0.f, 0.f, 0.f, 0.f};

    for (int kk = 0; kk < F_/BK; ++kk) {
        int k0 = kk * BK;
        #pragma unroll
        for (int i = 0; i < 4; ++i) {
            gl_lds16(pa[i] + k0, &lA[i*2048 + t*8]);
            gl_lds16(pb[i] + k0, &lB[i*2048 + t*8]);
        }
        asm volatile("s_waitcnt vmcnt(0)" ::: "memory");
        __syncthreads();
        #pragma unroll
        for (int s = 0; s < 2; ++s) {
            short8 af[4], bf[4];
            #pragma unroll
            for (int mi = 0; mi < 4; ++mi)
                af[mi] = *(const short8*)&lA[(wrow + mi*16 + lr)*BK + (((s*4+q) ^ xork) * 8)];
            #pragma unroll
            for (int ni = 0; ni < 4; ++ni)
                bf[ni] = *(const short8*)&lB[(wcol + ni*16 + lr)*BK + (((s*4+q) ^ xork) * 8)];
            #pragma unroll
            for (int mi = 0; mi < 4; ++mi)
                #pragma unroll
                for (int ni = 0; ni < 4; ++ni)
                    acc[mi][ni] = __builtin_amdgcn_mfma_f32_16x16x32_bf16(
                        af[mi], bf[ni], acc[mi][ni], 0, 0, 0);
        }
        __syncthreads();
    }

    const float* b2e = b2 + (size_t)e * D_;
    #pragma unroll
    for (int mi = 0; mi < 4; ++mi) {
        int gr = m0 + wrow + mi*16 + q*4;
        #pragma unroll
        for (int ni = 0; ni < 4; ++ni) {
            int dcol = n0 + wcol + ni*16 + lr;
            float bb = b2e[dcol];
            #pragma unroll
            for (int r = 0; r < 4; ++r)
                Y[(size_t)(gr + r) * D_ + dcol] = f2b(acc[mi][ni][r] + bb);
        }
    }
}

// ---------------- combine: out[t] = w0*Y[s0] + w1*Y[s1] ----------------
__global__ __launch_bounds__(256) void combine_kernel(
    const unsigned short* __restrict__ Y, const int* __restrict__ slots,
    const float* __restrict__ topw, float* __restrict__ out) {
    int t  = blockIdx.x;
    int d4 = threadIdx.x * 4;
    int s0 = slots[t*2], s1 = slots[t*2+1];
    float w0 = topw[t*2], w1 = topw[t*2+1];
    ushort4 y0 = *(const ushort4*)&Y[(size_t)s0 * D_ + d4];
    ushort4 y1 = *(const ushort4*)&Y[(size_t)s1 * D_ + d4];
    float4 o;
    o.x = w0*b2f(y0.x) + w1*b2f(y1.x);
    o.y = w0*b2f(y0.y) + w1*b2f(y1.y);
    o.z = w0*b2f(y0.z) + w1*b2f(y1.z);
    o.w = w0*b2f(y0.w) + w1*b2f(y1.w);
    *(float4*)&out[(size_t)t * D_ + d4] = o;
}

extern "C" void kernel_launch(void* const* d_in, const int* in_sizes, int n_in,
                              void* d_out, int out_size, void* d_ws, size_t ws_size,
                              hipStream_t stream) {
    const float* x  = (const float*)d_in[0];
    const float* Wg = (const float*)d_in[1];
    const float* bg = (const float*)d_in[2];
    const float* W1 = (const float*)d_in[3];
    const float* b1 = (const float*)d_in[4];
    const float* W2 = (const float*)d_in[5];
    const float* b2 = (const float*)d_in[6];
    float* out = (float*)d_out;

    char* wsp = (char*)d_ws;
    size_t off = 0;
    auto alloc = [&](size_t bytes) {
        void* p = wsp + off;
        off += (bytes + 255) & ~(size_t)255;
        return p;
    };
    int*   topi    = (int*)  alloc((size_t)NR_*4);
    float* topw    = (float*)alloc((size_t)NR_*4);
    int*   slots   = (int*)  alloc((size_t)NR_*4);
    int*   counts  = (int*)  alloc(E_*4);
    int*   offs    = (int*)  alloc((E_+1)*4);
    int*   cursors = (int*)  alloc(E_*4);
    int*   mb_e    = (int*)  alloc(MAXMB*4);
    int*   mb_m0   = (int*)  alloc(MAXMB*4);
    int*   perm    = (int*)  alloc((size_t)MAXP*4);
    unsigned short* Xb  = (unsigned short*)alloc((size_t)N_*D_*2);
    unsigned short* W1t = (unsigned short*)alloc((size_t)E_*D_*F_*2);
    unsigned short* W2t = (unsigned short*)alloc((size_t)E_*D_*F_*2);
    unsigned short* Hb  = (unsigned short*)alloc((size_t)MAXP*F_*2);
    unsigned short* Yb  = (unsigned short*)alloc((size_t)MAXP*D_*2);

    hipMemsetAsync(counts, 0, E_*4, stream);
    hipMemsetAsync(perm, 0, (size_t)MAXP*4, stream);

    gate_kernel<<<N_/4, 256, 0, stream>>>(x, Wg, bg, topi, topw, counts);
    scan_kernel<<<1, 64, 0, stream>>>(counts, offs, cursors, mb_e, mb_m0);
    scatter_kernel<<<N_/256, 256, 0, stream>>>(topi, cursors, perm, slots);
    castx_kernel<<<(N_*(size_t)D_/4)/256, 256, 0, stream>>>(x, Xb);
    tcast_kernel<<<dim3(D_/64, F_/64, E_), 256, 0, stream>>>(W1, W1t, D_, F_);
    tcast_kernel<<<dim3(F_/64, D_/64, E_), 256, 0, stream>>>(W2, W2t, F_, D_);
    ffn1_kernel<<<dim3(MAXMB, F_/128), 256, 0, stream>>>(Xb, W1t, b1, perm, mb_e, mb_m0, Hb);
    ffn2_kernel<<<dim3(MAXMB, D_/128), 256, 0, stream>>>(Hb, W2t, b2, mb_e, mb_m0, Yb);
    combine_kernel<<<N_, 256, 0, stream>>>(Yb, slots, topw, out);
}

// Round 2
// 946.880 us; speedup vs baseline: 1.1474x; 1.0927x over previous
//
#include <hip/hip_runtime.h>
#include <cstdint>

#define B_ 4
#define T_ 2048
#define D_ 1024
#define E_ 8
#define F_ 4096
#define K_ 2
#define N_ (B_*T_)      // 8192 tokens
#define NR_ (N_*K_)     // 16384 routed slots

#define TM 128
#define BK 64
#define MAXP (NR_ + E_*TM)       // padded slot capacity (17408)
#define MAXMB (NR_/TM + E_)      // max M-blocks (136) == 8 XCDs * 17
#define MBPX (MAXMB/8)           // 17 M-blocks per XCD chunk

typedef __attribute__((ext_vector_type(8))) short short8;
typedef __attribute__((ext_vector_type(4))) float f32x4;

typedef const __attribute__((address_space(1))) unsigned int* gp1_t;
typedef __attribute__((address_space(3))) unsigned int* lp3_t;

__device__ __forceinline__ void gl_lds16(const void* g, void* l) {
    __builtin_amdgcn_global_load_lds((gp1_t)g, (lp3_t)l, 16, 0, 0);
}

__device__ __forceinline__ unsigned short f2b(float f) {
    union { float f; unsigned int u; } v; v.f = f;
    unsigned int u = v.u;
    return (unsigned short)((u + 0x7FFFu + ((u >> 16) & 1u)) >> 16);
}

__device__ __forceinline__ float b2f(unsigned short u) {
    union { unsigned int i; float f; } v; v.i = ((unsigned int)u) << 16;
    return v.f;
}

__device__ __forceinline__ float gelu_exact(float x) {
    return 0.5f * x * (1.0f + erff(x * 0.70710678118654752440f));
}

// ---------------- gate: fp32 logits, top-2, softmax ----------------
__global__ __launch_bounds__(256) void gate_kernel(
    const float* __restrict__ x, const float* __restrict__ Wg,
    const float* __restrict__ bg, int* __restrict__ topi,
    float* __restrict__ topw, int* __restrict__ counts) {
    int tid  = threadIdx.x;
    int lane = tid & 63;
    int tok  = blockIdx.x * 4 + (tid >> 6);
    int e = lane & 7;
    int c = lane >> 3;
    const float4* xp = (const float4*)(x + (size_t)tok * D_ + c * 128);
    const float*  wp = Wg + (size_t)(c * 128) * E_ + e;
    float acc = 0.f;
    #pragma unroll 8
    for (int i = 0; i < 32; ++i) {
        float4 xv = xp[i];
        acc += xv.x * wp[(i*4+0)*E_];
        acc += xv.y * wp[(i*4+1)*E_];
        acc += xv.z * wp[(i*4+2)*E_];
        acc += xv.w * wp[(i*4+3)*E_];
    }
    acc += __shfl_xor(acc, 8, 64);
    acc += __shfl_xor(acc, 16, 64);
    acc += __shfl_xor(acc, 32, 64);
    float logit = acc + bg[e];
    float v1 = -3.4e38f, v2 = -3.4e38f; int i1 = -1, i2 = -1;
    for (int ee = 0; ee < 8; ++ee) {
        float le = __shfl(logit, ee, 64);
        if (le > v1) { v2 = v1; i2 = i1; v1 = le; i1 = ee; }
        else if (le > v2) { v2 = le; i2 = ee; }
    }
    if (lane == 0) {
        float p2 = expf(v2 - v1);
        float s  = 1.0f + p2;
        topi[tok*2]   = i1; topw[tok*2]   = 1.0f / s;
        topi[tok*2+1] = i2; topw[tok*2+1] = p2 / s;
        atomicAdd(&counts[i1], 1);    // fire-and-forget (no return use)
        atomicAdd(&counts[i2], 1);
    }
}

// scan: padded offsets + flat M-block tables
__global__ void scan_kernel(const int* __restrict__ counts,
                            int* __restrict__ offs, int* __restrict__ cursors,
                            int* __restrict__ mb_e, int* __restrict__ mb_m0) {
    if (threadIdx.x == 0) {
        int s = 0, mb = 0;
        for (int e = 0; e < E_; ++e) {
            offs[e] = s; cursors[e] = s;
            int nb = (counts[e] + TM - 1) / TM;
            for (int i = 0; i < nb; ++i) { mb_e[mb] = e; mb_m0[mb] = s + i*TM; ++mb; }
            s += nb * TM;
        }
        offs[E_] = s;
        for (int b = mb; b < MAXMB; ++b) mb_e[b] = -1;
    }
}

// wave-aggregated scatter: ~16 atomics/wave instead of 128 contended ones
__global__ __launch_bounds__(256) void scatter_kernel(
    const int* __restrict__ topi, int* __restrict__ cursors,
    int* __restrict__ perm, int* __restrict__ slots) {
    int t = blockIdx.x * blockDim.x + threadIdx.x;
    int lane = threadIdx.x & 63;
    unsigned long long lanebit_m1 = (lane == 63) ? ~0ULL >> 1
                                  : ((1ULL << (lane & 63)) - 1ULL);
    // recompute exactly: bits below this lane
    lanebit_m1 = (1ULL << lane) - 1ULL;   // lane<64 so shift is valid for lane<63; lane==63 ok: 1<<63 defined for ull
    #pragma unroll
    for (int k = 0; k < K_; ++k) {
        int e = (t < N_) ? topi[t*2 + k] : -1;
        int pos = 0;
        #pragma unroll
        for (int ee = 0; ee < E_; ++ee) {
            unsigned long long mask = __ballot(e == ee);
            if (mask) {
                int leader = __ffsll((long long)mask) - 1;
                int base = 0;
                if (lane == leader)
                    base = atomicAdd(&cursors[ee], __popcll(mask));
                base = __shfl(base, leader, 64);
                if (e == ee)
                    pos = base + __popcll(mask & lanebit_m1);
            }
        }
        if (t < N_) {
            perm[pos] = t;
            slots[t*2 + k] = pos;
        }
    }
}

// ---------------- casts ----------------
__global__ __launch_bounds__(256) void castx_kernel(
    const float* __restrict__ x, unsigned short* __restrict__ xb) {
    int i = blockIdx.x * blockDim.x + threadIdx.x;   // over N*D/4
    float4 v = ((const float4*)x)[i];
    ushort4 o; o.x = f2b(v.x); o.y = f2b(v.y); o.z = f2b(v.z); o.w = f2b(v.w);
    ((ushort4*)xb)[i] = o;
}

// batched fp32 [R,C] -> bf16 [C,R]; 64x64 tile, vectorized
__global__ __launch_bounds__(256) void tcast_kernel(
    const float* __restrict__ src, unsigned short* __restrict__ dst, int R, int C) {
    __shared__ float tile[64][65];
    int rb = blockIdx.x * 64, cb = blockIdx.y * 64;
    const float* s = src + (size_t)blockIdx.z * R * C;
    unsigned short* d = dst + (size_t)blockIdx.z * R * C;
    int tx = threadIdx.x & 15, ty = threadIdx.x >> 4;   // 16 x 16
    #pragma unroll
    for (int i = 0; i < 4; ++i) {
        int r = ty + i*16;
        float4 v = *(const float4*)&s[(size_t)(rb + r) * C + cb + tx*4];
        tile[r][tx*4+0] = v.x; tile[r][tx*4+1] = v.y;
        tile[r][tx*4+2] = v.z; tile[r][tx*4+3] = v.w;
    }
    __syncthreads();
    #pragma unroll
    for (int i = 0; i < 4; ++i) {
        int c = ty + i*16;                               // dst row
        ushort4 o;
        o.x = f2b(tile[tx*4+0][c]);
        o.y = f2b(tile[tx*4+1][c]);
        o.z = f2b(tile[tx*4+2][c]);
        o.w = f2b(tile[tx*4+3][c]);
        *(ushort4*)&d[(size_t)(cb + c) * R + rb + tx*4] = o;
    }
}

// ---------------- GEMM1: H = gelu(Xb[perm] @ W1[e] + b1[e]) ----------------
// 128x128 tile, BK=64; logical grid (MAXMB, F/128); acc 4x4, 4 waves/SIMD.
// XCD chunk swizzle: HW assigns XCD = flat%8 (verified: round-1 FETCH=548MB
// == 35MB A + 8x64MB B exactly). Give each XCD a 17-mb strip x all 32 f so
// B panels are consumed by co-resident blocks on ONE XCD. mb-fastest within
// chunk: 17 A panels (4.4MB) cycle in L2, B panels stream.
__global__ __launch_bounds__(256, 4) void ffn1_kernel(
    const unsigned short* __restrict__ Xb, const unsigned short* __restrict__ W1t,
    const float* __restrict__ b1, const int* __restrict__ perm,
    const int* __restrict__ mb_e, const int* __restrict__ mb_m0,
    unsigned short* __restrict__ H) {
    int o   = blockIdx.x + gridDim.x * blockIdx.y;   // 0..4351
    int xcd = o & 7;
    int j   = o >> 3;                                // 0..543 = 17*32
    int mbi = xcd * MBPX + (j % MBPX);
    int nbi = j / MBPX;                              // 0..31
    int e = mb_e[mbi];
    if (e < 0) return;
    int m0 = mb_m0[mbi];
    int n0 = nbi * 128;
    const unsigned short* Bw = W1t + (size_t)e * F_ * D_;

    __shared__ __align__(16) unsigned short lA[128*BK];   // 16 KB
    __shared__ __align__(16) unsigned short lB[128*BK];   // 16 KB

    int t = threadIdx.x;
    int lane = t & 63;
    int wv = t >> 6;
    int wrow = (wv >> 1) * 64, wcol = (wv & 1) * 64;
    int lr = lane & 15, q = lane >> 4;
    int xork = lr & 7;        // read-side swizzle key (row&7 == lr&7)

    int sr = t >> 3;          // staging row 0..31 per pass
    int sc = ((t & 7) ^ (sr & 7)) * 8;   // pre-swizzled source chunk (ushorts)
    const unsigned short* pa[4];
    const unsigned short* pb[4];
    #pragma unroll
    for (int i = 0; i < 4; ++i) {
        int tok = perm[m0 + sr + 32*i];
        pa[i] = Xb + (size_t)tok * D_ + sc;
        pb[i] = Bw + (size_t)(n0 + sr + 32*i) * D_ + sc;
    }

    f32x4 acc[4][4];
    #pragma unroll
    for (int mi = 0; mi < 4; ++mi)
        #pragma unroll
        for (int ni = 0; ni < 4; ++ni)
            acc[mi][ni] = (f32x4){0.f, 0.f, 0.f, 0.f};

    for (int kk = 0; kk < D_/BK; ++kk) {
        int k0 = kk * BK;
        #pragma unroll
        for (int i = 0; i < 4; ++i) {
            gl_lds16(pa[i] + k0, &lA[i*2048 + t*8]);
            gl_lds16(pb[i] + k0, &lB[i*2048 + t*8]);
        }
        asm volatile("s_waitcnt vmcnt(0)" ::: "memory");
        __syncthreads();
        #pragma unroll
        for (int s = 0; s < 2; ++s) {
            short8 af[4], bf[4];
            #pragma unroll
            for (int mi = 0; mi < 4; ++mi)
                af[mi] = *(const short8*)&lA[(wrow + mi*16 + lr)*BK + (((s*4+q) ^ xork) * 8)];
            #pragma unroll
            for (int ni = 0; ni < 4; ++ni)
                bf[ni] = *(const short8*)&lB[(wcol + ni*16 + lr)*BK + (((s*4+q) ^ xork) * 8)];
            #pragma unroll
            for (int mi = 0; mi < 4; ++mi)
                #pragma unroll
                for (int ni = 0; ni < 4; ++ni)
                    acc[mi][ni] = __builtin_amdgcn_mfma_f32_16x16x32_bf16(
                        af[mi], bf[ni], acc[mi][ni], 0, 0, 0);
        }
        __syncthreads();
    }

    const float* b1e = b1 + (size_t)e * F_;
    #pragma unroll
    for (int mi = 0; mi < 4; ++mi) {
        int gr = m0 + wrow + mi*16 + q*4;
        #pragma unroll
        for (int ni = 0; ni < 4; ++ni) {
            int f = n0 + wcol + ni*16 + lr;
            float bb = b1e[f];
            #pragma unroll
            for (int r = 0; r < 4; ++r) {
                float h = gelu_exact(acc[mi][ni][r] + bb);
                H[(size_t)(gr + r) * F_ + f] = f2b(h);
            }
        }
    }
}

// ---------------- GEMM2: Y[p] = H[p] @ W2[e] + b2[e] (bf16 stores) ---------
// 128x128 tile, BK=64; logical grid (MAXMB, D/128)=1088 wg; same XCD chunking.
__global__ __launch_bounds__(256, 4) void ffn2_kernel(
    const unsigned short* __restrict__ H, const unsigned short* __restrict__ W2t,
    const float* __restrict__ b2,
    const int* __restrict__ mb_e, const int* __restrict__ mb_m0,
    unsigned short* __restrict__ Y) {
    int o   = blockIdx.x + gridDim.x * blockIdx.y;   // 0..1087
    int xcd = o & 7;
    int j   = o >> 3;                                // 0..135 = 17*8
    int mbi = xcd * MBPX + (j % MBPX);
    int nbi = j / MBPX;                              // 0..7
    int e = mb_e[mbi];
    if (e < 0) return;
    int m0 = mb_m0[mbi];
    int n0 = nbi * 128;
    const unsigned short* Bw = W2t + (size_t)e * D_ * F_;

    __shared__ __align__(16) unsigned short lA[128*BK];   // 16 KB
    __shared__ __align__(16) unsigned short lB[128*BK];   // 16 KB

    int t = threadIdx.x;
    int lane = t & 63;
    int wv = t >> 6;
    int wrow = (wv >> 1) * 64, wcol = (wv & 1) * 64;
    int lr = lane & 15, q = lane >> 4;
    int xork = lr & 7;

    int sr = t >> 3;
    int sc = ((t & 7) ^ (sr & 7)) * 8;   // pre-swizzled source chunk
    const unsigned short* pa[4];
    const unsigned short* pb[4];
    #pragma unroll
    for (int i = 0; i < 4; ++i) {
        pa[i] = H  + (size_t)(m0 + sr + 32*i) * F_ + sc;
        pb[i] = Bw + (size_t)(n0 + sr + 32*i) * F_ + sc;
    }

    f32x4 acc[4][4];
    #pragma unroll
    for (int mi = 0; mi < 4; ++mi)
        #pragma unroll
        for (int ni = 0; ni < 4; ++ni)
            acc[mi][ni] = (f32x4){0.f, 0.f, 0.f, 0.f};

    for (int kk = 0; kk < F_/BK; ++kk) {
        int k0 = kk * BK;
        #pragma unroll
        for (int i = 0; i < 4; ++i) {
            gl_lds16(pa[i] + k0, &lA[i*2048 + t*8]);
            gl_lds16(pb[i] + k0, &lB[i*2048 + t*8]);
        }
        asm volatile("s_waitcnt vmcnt(0)" ::: "memory");
        __syncthreads();
        #pragma unroll
        for (int s = 0; s < 2; ++s) {
            short8 af[4], bf[4];
            #pragma unroll
            for (int mi = 0; mi < 4; ++mi)
                af[mi] = *(const short8*)&lA[(wrow + mi*16 + lr)*BK + (((s*4+q) ^ xork) * 8)];
            #pragma unroll
            for (int ni = 0; ni < 4; ++ni)
                bf[ni] = *(const short8*)&lB[(wcol + ni*16 + lr)*BK + (((s*4+q) ^ xork) * 8)];
            #pragma unroll
            for (int mi = 0; mi < 4; ++mi)
                #pragma unroll
                for (int ni = 0; ni < 4; ++ni)
                    acc[mi][ni] = __builtin_amdgcn_mfma_f32_16x16x32_bf16(
                        af[mi], bf[ni], acc[mi][ni], 0, 0, 0);
        }
        __syncthreads();
    }

    const float* b2e = b2 + (size_t)e * D_;
    #pragma unroll
    for (int mi = 0; mi < 4; ++mi) {
        int gr = m0 + wrow + mi*16 + q*4;
        #pragma unroll
        for (int ni = 0; ni < 4; ++ni) {
            int dcol = n0 + wcol + ni*16 + lr;
            float bb = b2e[dcol];
            #pragma unroll
            for (int r = 0; r < 4; ++r)
                Y[(size_t)(gr + r) * D_ + dcol] = f2b(acc[mi][ni][r] + bb);
        }
    }
}

// ---------------- combine: out[t] = w0*Y[s0] + w1*Y[s1] ----------------
__global__ __launch_bounds__(256) void combine_kernel(
    const unsigned short* __restrict__ Y, const int* __restrict__ slots,
    const float* __restrict__ topw, float* __restrict__ out) {
    int t  = blockIdx.x;
    int d4 = threadIdx.x * 4;
    int s0 = slots[t*2], s1 = slots[t*2+1];
    float w0 = topw[t*2], w1 = topw[t*2+1];
    ushort4 y0 = *(const ushort4*)&Y[(size_t)s0 * D_ + d4];
    ushort4 y1 = *(const ushort4*)&Y[(size_t)s1 * D_ + d4];
    float4 o;
    o.x = w0*b2f(y0.x) + w1*b2f(y1.x);
    o.y = w0*b2f(y0.y) + w1*b2f(y1.y);
    o.z = w0*b2f(y0.z) + w1*b2f(y1.z);
    o.w = w0*b2f(y0.w) + w1*b2f(y1.w);
    *(float4*)&out[(size_t)t * D_ + d4] = o;
}

extern "C" void kernel_launch(void* const* d_in, const int* in_sizes, int n_in,
                              void* d_out, int out_size, void* d_ws, size_t ws_size,
                              hipStream_t stream) {
    const float* x  = (const float*)d_in[0];
    const float* Wg = (const float*)d_in[1];
    const float* bg = (const float*)d_in[2];
    const float* W1 = (const float*)d_in[3];
    const float* b1 = (const float*)d_in[4];
    const float* W2 = (const float*)d_in[5];
    const float* b2 = (const float*)d_in[6];
    float* out = (float*)d_out;

    char* wsp = (char*)d_ws;
    size_t off = 0;
    auto alloc = [&](size_t bytes) {
        void* p = wsp + off;
        off += (bytes + 255) & ~(size_t)255;
        return p;
    };
    int*   topi    = (int*)  alloc((size_t)NR_*4);
    float* topw    = (float*)alloc((size_t)NR_*4);
    int*   slots   = (int*)  alloc((size_t)NR_*4);
    int*   counts  = (int*)  alloc(E_*4);
    int*   offs    = (int*)  alloc((E_+1)*4);
    int*   cursors = (int*)  alloc(E_*4);
    int*   mb_e    = (int*)  alloc(MAXMB*4);
    int*   mb_m0   = (int*)  alloc(MAXMB*4);
    int*   perm    = (int*)  alloc((size_t)MAXP*4);
    unsigned short* Xb  = (unsigned short*)alloc((size_t)N_*D_*2);
    unsigned short* W1t = (unsigned short*)alloc((size_t)E_*D_*F_*2);
    unsigned short* W2t = (unsigned short*)alloc((size_t)E_*D_*F_*2);
    unsigned short* Hb  = (unsigned short*)alloc((size_t)MAXP*F_*2);
    unsigned short* Yb  = (unsigned short*)alloc((size_t)MAXP*D_*2);

    hipMemsetAsync(counts, 0, E_*4, stream);
    hipMemsetAsync(perm, 0, (size_t)MAXP*4, stream);

    gate_kernel<<<N_/4, 256, 0, stream>>>(x, Wg, bg, topi, topw, counts);
    scan_kernel<<<1, 64, 0, stream>>>(counts, offs, cursors, mb_e, mb_m0);
    scatter_kernel<<<N_/256, 256, 0, stream>>>(topi, cursors, perm, slots);
    castx_kernel<<<(N_*(size_t)D_/4)/256, 256, 0, stream>>>(x, Xb);
    tcast_kernel<<<dim3(D_/64, F_/64, E_), 256, 0, stream>>>(W1, W1t, D_, F_);
    tcast_kernel<<<dim3(F_/64, D_/64, E_), 256, 0, stream>>>(W2, W2t, F_, D_);
    ffn1_kernel<<<dim3(MAXMB, F_/128), 256, 0, stream>>>(Xb, W1t, b1, perm, mb_e, mb_m0, Hb);
    ffn2_kernel<<<dim3(MAXMB, D_/128), 256, 0, stream>>>(Hb, W2t, b2, mb_e, mb_m0, Yb);
    combine_kernel<<<N_, 256, 0, stream>>>(Yb, slots, topw, out);
}